// Round 6
// baseline (1181.292 us; speedup 1.0000x reference)
//
#include <hip/hip_runtime.h>
#include <hip/hip_bf16.h>

#define B_ 4
#define S_ 2048
#define DIN 2048
#define DST 2048
#define DOUT 2048
#define NH 16
#define HH 128
#define M_ (B_ * S_)          // 8192
#define OUT_OFF ((size_t)M_ * DOUT)  // 16777216

typedef __attribute__((ext_vector_type(8))) __bf16 bf16x8;
typedef __attribute__((ext_vector_type(4))) float f32x4;
typedef __attribute__((ext_vector_type(2))) _Float16 f16x2;

__device__ __forceinline__ unsigned short f2bf(float f) {
    unsigned int u = __float_as_uint(f);
    unsigned int r = u + 0x7FFFu + ((u >> 16) & 1u);
    return (unsigned short)(r >> 16);
}

__device__ __forceinline__ float fdot2(f16x2 a, f16x2 b, float c) {
#if __has_builtin(__builtin_amdgcn_fdot2)
    return __builtin_amdgcn_fdot2(a, b, c, false);
#else
    return fmaf((float)a.x, (float)b.x, fmaf((float)a.y, (float)b.y, c));
#endif
}

__device__ __forceinline__ void gload_lds16(const void* g, void* l) {
    __builtin_amdgcn_global_load_lds(
        (const __attribute__((address_space(1))) void*)g,
        (__attribute__((address_space(3))) void*)l, 16, 0, 0);
}

// ---------------- cast x (fp32 -> bf16), 8 elems/thread ----------------
__global__ __launch_bounds__(256) void k_cast_bf16(
    const float* __restrict__ in, unsigned short* __restrict__ out, int n8) {
    int i = blockIdx.x * 256 + threadIdx.x;
    if (i >= n8) return;
    const float4* p = ((const float4*)in) + (size_t)i * 2;
    float4 a = p[0], b = p[1];
    ushort4 r0, r1;
    r0.x = f2bf(a.x); r0.y = f2bf(a.y); r0.z = f2bf(a.z); r0.w = f2bf(a.w);
    r1.x = f2bf(b.x); r1.y = f2bf(b.y); r1.z = f2bf(b.z); r1.w = f2bf(b.w);
    ushort4* o = ((ushort4*)out) + (size_t)i * 2;
    o[0] = r0; o[1] = r1;
}

// ------------- transpose + cast: in[K][N] fp32 -> out[N][K] bf16 -------------
__global__ __launch_bounds__(256) void k_transpose_bf16(
    const float* __restrict__ in, unsigned short* __restrict__ out, int K, int N) {
    __shared__ float tile[64][65];
    int k0 = blockIdx.y * 64, n0 = blockIdx.x * 64;
    int tr  = threadIdx.x >> 4;          // 0..15
    int tc4 = (threadIdx.x & 15) * 4;    // 0..60
#pragma unroll
    for (int p = 0; p < 4; ++p) {
        int r = tr + p * 16;
        float4 v = *(const float4*)&in[(size_t)(k0 + r) * N + n0 + tc4];
        tile[r][tc4 + 0] = v.x; tile[r][tc4 + 1] = v.y;
        tile[r][tc4 + 2] = v.z; tile[r][tc4 + 3] = v.w;
    }
    __syncthreads();
#pragma unroll
    for (int p = 0; p < 4; ++p) {
        int n = tr + p * 16;
        ushort4 o;
        o.x = f2bf(tile[tc4 + 0][n]); o.y = f2bf(tile[tc4 + 1][n]);
        o.z = f2bf(tile[tc4 + 2][n]); o.w = f2bf(tile[tc4 + 3][n]);
        *(ushort4*)&out[(size_t)(n0 + n) * K + k0 + tc4] = o;
    }
}

// ---------------- bf16 GEMM: C[M][N] = A[M][K] * Bt[N][K]^T (+bias) ----------------
__global__ __launch_bounds__(256, 2) void k_gemm_bt(
    const unsigned short* __restrict__ A,
    const unsigned short* __restrict__ Bt,
    float* __restrict__ C,
    const float* __restrict__ bias,
    int M, int N, int K, int hasBias) {
    __shared__ unsigned short As[128 * 64];
    __shared__ unsigned short Bs[128 * 64];
    const int tid  = threadIdx.x;
    const int lane = tid & 63;
    const int wid  = tid >> 6;
    const int wr = wid >> 1, wc = wid & 1;
    const int row0 = blockIdx.y * 128, col0 = blockIdx.x * 128;

    f32x4 acc[4][4];
#pragma unroll
    for (int m = 0; m < 4; ++m)
#pragma unroll
        for (int n = 0; n < 4; ++n) acc[m][n] = (f32x4)(0.f);

    const char* Abase = (const char*)(A + (size_t)row0 * K);
    const char* Bbase = (const char*)(Bt + (size_t)col0 * K);

    int srow[4], skb[4];
#pragma unroll
    for (int i = 0; i < 4; ++i) {
        unsigned o = (unsigned)(i * 256 + tid) * 16u;
        unsigned l = o ^ (((o >> 7) & 7u) << 4);   // inverse-swizzled linear index
        srow[i] = (int)(l >> 7);
        skb[i]  = (int)(l & 127u);
    }

    for (int kt = 0; kt < K; kt += 64) {
#pragma unroll
        for (int i = 0; i < 4; ++i) {
            unsigned o = (unsigned)(i * 256 + tid) * 16u;
            gload_lds16(Abase + (size_t)srow[i] * (K * 2) + (size_t)kt * 2 + skb[i],
                        (char*)As + o);
            gload_lds16(Bbase + (size_t)srow[i] * (K * 2) + (size_t)kt * 2 + skb[i],
                        (char*)Bs + o);
        }
        asm volatile("s_waitcnt vmcnt(0)" ::: "memory");
        __syncthreads();
#pragma unroll
        for (int ks = 0; ks < 2; ++ks) {
            bf16x8 af[4], bfr[4];
#pragma unroll
            for (int m = 0; m < 4; ++m) {
                int row = wr * 64 + m * 16 + (lane & 15);
                unsigned o = (unsigned)(row * 128 + ks * 64 + ((lane >> 4) * 16));
                o ^= ((unsigned)(row & 7) << 4);
                af[m] = *(const bf16x8*)((const char*)As + o);
            }
#pragma unroll
            for (int n = 0; n < 4; ++n) {
                int col = wc * 64 + n * 16 + (lane & 15);
                unsigned o = (unsigned)(col * 128 + ks * 64 + ((lane >> 4) * 16));
                o ^= ((unsigned)(col & 7) << 4);
                bfr[n] = *(const bf16x8*)((const char*)Bs + o);
            }
#pragma unroll
            for (int m = 0; m < 4; ++m)
#pragma unroll
                for (int n = 0; n < 4; ++n)
                    acc[m][n] = __builtin_amdgcn_mfma_f32_16x16x32_bf16(
                        af[m], bfr[n], acc[m][n], 0, 0, 0);
        }
        __syncthreads();
    }

#pragma unroll
    for (int n = 0; n < 4; ++n) {
        int gcol = col0 + wc * 64 + n * 16 + (lane & 15);
        float bv = hasBias ? bias[gcol] : 0.f;
#pragma unroll
        for (int m = 0; m < 4; ++m) {
            int growb = row0 + wr * 64 + m * 16 + ((lane >> 4) * 4);
            float* cp = C + (size_t)growb * N + gcol;
#pragma unroll
            for (int r = 0; r < 4; ++r) cp[(size_t)r * N] = acc[m][n][r] + bv;
        }
    }
}

// ---------------- RNN scan v6: ONE WAVE = ONE CHAIN, zero barriers ----------------
// 16 blocks x 4 waves; wave w of block g owns chain = g*4+w (b = chain>>4,
// n = chain&15). Lane owns output cols 2l, 2l+1 with ALL 128 weight rows in
// VGPRs (128 f16x2). h: wave-private 256B LDS buffer, read as 16 broadcast
// ds_read_b128 (all lanes same address -> conflict-free multicast). Full dot
// reduction in-lane: no shfl/DPP/barrier. Same-wave DS program order makes
// the single buffer safe; the compiler inserts the lgkmcnt waits.
__global__ __attribute__((amdgpu_flat_work_group_size(256, 256),
                          amdgpu_waves_per_eu(1, 1))) void k_scan(
    const float* __restrict__ xp,        // [M_][2048] fp32
    const float* __restrict__ h0,        // [B_][2048]
    const float* __restrict__ sw,        // [NH][HH][HH]
    unsigned short* __restrict__ hsb,    // [M_][2048] bf16 out
    float* __restrict__ out_state) {     // [B_][2048] fp32
    __shared__ __align__(16) unsigned hbuf[4][64];
    const int tid  = threadIdx.x;
    const int lane = tid & 63;
    const int wv   = tid >> 6;
    const int chain = blockIdx.x * 4 + wv;    // 0..63
    const int bb = chain >> 4;
    const int nn = chain & 15;
    const int c0 = lane * 2;

    // wA[k] = (W[2k][c0], W[2k+1][c0]); wB[k] = same for col c0+1
    const float* wb = sw + (size_t)nn * HH * HH;
    f16x2 wA[64], wB[64];
#pragma unroll
    for (int k = 0; k < 64; ++k) {
        const float* r0p = wb + (size_t)(2 * k) * HH + c0;
        const float* r1p = r0p + HH;
        wA[k] = f16x2{(_Float16)r0p[0], (_Float16)r1p[0]};
        wB[k] = f16x2{(_Float16)r0p[1], (_Float16)r1p[1]};
    }

    {   // init h (own dword)
        float2 h2 = *(const float2*)(h0 + bb * DST + nn * HH + c0);
        unsigned lo = __builtin_bit_cast(unsigned short, (_Float16)h2.x);
        unsigned hi = __builtin_bit_cast(unsigned short, (_Float16)h2.y);
        hbuf[wv][lane] = lo | (hi << 16);
    }

    const float2* xrow2 = (const float2*)(xp + (size_t)bb * S_ * DST + nn * HH) + lane;
    unsigned* hrow32 = (unsigned*)(hsb + (size_t)bb * S_ * DST + nn * HH) + lane;
    float* osp = out_state + bb * DST + nn * HH + c0;

    // 4-deep xp prefetch
    float2 xq0 = xrow2[0];
    float2 xq1 = xrow2[(size_t)(DST / 2)];
    float2 xq2 = xrow2[(size_t)2 * (DST / 2)];
    float2 xq3 = xrow2[(size_t)3 * (DST / 2)];

    const uint4* hp = (const uint4*)&hbuf[wv][0];

    for (int t = 0; t < S_; ++t) {
        int tpf = (t + 4 < S_) ? t + 4 : S_ - 1;
        float2 xq4 = xrow2[(size_t)tpf * (DST / 2)];

        float a0 = 0.f, a1 = 0.f, a2 = 0.f, a3 = 0.f;
        float b0 = 0.f, b1 = 0.f, b2 = 0.f, b3 = 0.f;
#define DOT1(u, k, A, Bv) { f16x2 hk = __builtin_bit_cast(f16x2, (unsigned)(u)); \
        A = fdot2(hk, wA[k], A); Bv = fdot2(hk, wB[k], Bv); }
#pragma unroll
        for (int j = 0; j < 16; ++j) {
            uint4 R = hp[j];
            DOT1(R.x, 4 * j + 0, a0, b0)
            DOT1(R.y, 4 * j + 1, a1, b1)
            DOT1(R.z, 4 * j + 2, a2, b2)
            DOT1(R.w, 4 * j + 3, a3, b3)
        }
#undef DOT1
        float s0 = ((a0 + a1) + (a2 + a3)) + xq0.x;
        float s1 = ((b0 + b1) + (b2 + b3)) + xq0.y;
        // tanh(s) = 1 - 2/(exp(2s)+1), exact at +-inf
        float e0 = __builtin_amdgcn_exp2f(s0 * 2.885390081777927f);
        float e1 = __builtin_amdgcn_exp2f(s1 * 2.885390081777927f);
        float th0 = fmaf(-2.f, __builtin_amdgcn_rcpf(e0 + 1.f), 1.f);
        float th1 = fmaf(-2.f, __builtin_amdgcn_rcpf(e1 + 1.f), 1.f);

        unsigned lo = __builtin_bit_cast(unsigned short, (_Float16)th0);
        unsigned hi = __builtin_bit_cast(unsigned short, (_Float16)th1);
        hbuf[wv][lane] = lo | (hi << 16);
        hrow32[(size_t)t * (DST / 2)] = (unsigned)f2bf(th0) | ((unsigned)f2bf(th1) << 16);
        if (t == S_ - 1) { osp[0] = th0; osp[1] = th1; }

        xq0 = xq1; xq1 = xq2; xq2 = xq3; xq3 = xq4;
    }
}

extern "C" void kernel_launch(void* const* d_in, const int* in_sizes, int n_in,
                              void* d_out, int out_size, void* d_ws, size_t ws_size,
                              hipStream_t stream) {
    const float* x    = (const float*)d_in[0];
    const float* h0   = (const float*)d_in[1];
    const float* Wi   = (const float*)d_in[2];
    const float* bias = (const float*)d_in[3];
    const float* sw   = (const float*)d_in[4];
    const float* Wo   = (const float*)d_in[5];
    float* out = (float*)d_out;

    char* ws = (char*)d_ws;
    unsigned short* xb  = (unsigned short*)ws;                     // 32MB (reused as hs bf16)
    unsigned short* wit = (unsigned short*)(ws + 33554432);        // 8MB
    unsigned short* wot = (unsigned short*)(ws + 41943040);        // 8MB
    float*          xp  = (float*)(ws + 50331648);                 // 64MB

    // 1. cast x -> bf16
    k_cast_bf16<<<8192, 256, 0, stream>>>(x, xb, (M_ * DIN) / 8);
    // 2. transpose+cast weights
    dim3 tg(32, 32);
    k_transpose_bf16<<<tg, 256, 0, stream>>>(Wi, wit, DIN, DST);
    k_transpose_bf16<<<tg, 256, 0, stream>>>(Wo, wot, DST, DOUT);
    // 3. xp = x @ Wi + b   (fp32 out)
    dim3 g1(DST / 128, M_ / 128);
    k_gemm_bt<<<g1, 256, 0, stream>>>(xb, wit, xp, bias, M_, DST, DIN, 1);
    // 4. sequential scan (one wave per chain, 16 blocks x 4 waves)
    k_scan<<<16, 256, 0, stream>>>(xp, h0, sw, xb, out + OUT_OFF);
    // 5. out = hs @ Wo
    dim3 g2(DOUT / 128, M_ / 128);
    k_gemm_bt<<<g2, 256, 0, stream>>>(xb, wot, out, nullptr, M_, DOUT, DST, 0);
}

// Round 7
// 1041.139 us; speedup vs baseline: 1.1346x; 1.1346x over previous
//
#include <hip/hip_runtime.h>
#include <hip/hip_bf16.h>

#define B_ 4
#define S_ 2048
#define DIN 2048
#define DST 2048
#define DOUT 2048
#define NH 16
#define HH 128
#define M_ (B_ * S_)          // 8192
#define OUT_OFF ((size_t)M_ * DOUT)  // 16777216

typedef __attribute__((ext_vector_type(8))) __bf16 bf16x8;
typedef __attribute__((ext_vector_type(4))) float f32x4;
typedef __attribute__((ext_vector_type(2))) _Float16 f16x2;

__device__ __forceinline__ unsigned short f2bf(float f) {
    unsigned int u = __float_as_uint(f);
    unsigned int r = u + 0x7FFFu + ((u >> 16) & 1u);
    return (unsigned short)(r >> 16);
}

__device__ __forceinline__ float fdot2(f16x2 a, f16x2 b, float c) {
#if __has_builtin(__builtin_amdgcn_fdot2)
    return __builtin_amdgcn_fdot2(a, b, c, false);
#else
    return fmaf((float)a.x, (float)b.x, fmaf((float)a.y, (float)b.y, c));
#endif
}

// quad_perm DPP: 0xB1 = swap within lane pairs (register-only cross-lane)
#define DPP_PULL(v, ctrl) __builtin_bit_cast(float, \
    __builtin_amdgcn_mov_dpp(__builtin_bit_cast(int, (v)), (ctrl), 0xf, 0xf, true))

__device__ __forceinline__ void gload_lds16(const void* g, void* l) {
    __builtin_amdgcn_global_load_lds(
        (const __attribute__((address_space(1))) void*)g,
        (__attribute__((address_space(3))) void*)l, 16, 0, 0);
}

// ---------------- cast x (fp32 -> bf16), 8 elems/thread ----------------
__global__ __launch_bounds__(256) void k_cast_bf16(
    const float* __restrict__ in, unsigned short* __restrict__ out, int n8) {
    int i = blockIdx.x * 256 + threadIdx.x;
    if (i >= n8) return;
    const float4* p = ((const float4*)in) + (size_t)i * 2;
    float4 a = p[0], b = p[1];
    ushort4 r0, r1;
    r0.x = f2bf(a.x); r0.y = f2bf(a.y); r0.z = f2bf(a.z); r0.w = f2bf(a.w);
    r1.x = f2bf(b.x); r1.y = f2bf(b.y); r1.z = f2bf(b.z); r1.w = f2bf(b.w);
    ushort4* o = ((ushort4*)out) + (size_t)i * 2;
    o[0] = r0; o[1] = r1;
}

// ------------- transpose + cast: in[K][N] fp32 -> out[N][K] bf16 -------------
__global__ __launch_bounds__(256) void k_transpose_bf16(
    const float* __restrict__ in, unsigned short* __restrict__ out, int K, int N) {
    __shared__ float tile[64][65];
    int k0 = blockIdx.y * 64, n0 = blockIdx.x * 64;
    int tr  = threadIdx.x >> 4;          // 0..15
    int tc4 = (threadIdx.x & 15) * 4;    // 0..60
#pragma unroll
    for (int p = 0; p < 4; ++p) {
        int r = tr + p * 16;
        float4 v = *(const float4*)&in[(size_t)(k0 + r) * N + n0 + tc4];
        tile[r][tc4 + 0] = v.x; tile[r][tc4 + 1] = v.y;
        tile[r][tc4 + 2] = v.z; tile[r][tc4 + 3] = v.w;
    }
    __syncthreads();
#pragma unroll
    for (int p = 0; p < 4; ++p) {
        int n = tr + p * 16;
        ushort4 o;
        o.x = f2bf(tile[tc4 + 0][n]); o.y = f2bf(tile[tc4 + 1][n]);
        o.z = f2bf(tile[tc4 + 2][n]); o.w = f2bf(tile[tc4 + 3][n]);
        *(ushort4*)&out[(size_t)(n0 + n) * K + k0 + tc4] = o;
    }
}

// ---------------- bf16 GEMM: C[M][N] = A[M][K] * Bt[N][K]^T (+bias) ----------------
__global__ __launch_bounds__(256, 2) void k_gemm_bt(
    const unsigned short* __restrict__ A,
    const unsigned short* __restrict__ Bt,
    float* __restrict__ C,
    const float* __restrict__ bias,
    int M, int N, int K, int hasBias) {
    __shared__ unsigned short As[128 * 64];
    __shared__ unsigned short Bs[128 * 64];
    const int tid  = threadIdx.x;
    const int lane = tid & 63;
    const int wid  = tid >> 6;
    const int wr = wid >> 1, wc = wid & 1;
    const int row0 = blockIdx.y * 128, col0 = blockIdx.x * 128;

    f32x4 acc[4][4];
#pragma unroll
    for (int m = 0; m < 4; ++m)
#pragma unroll
        for (int n = 0; n < 4; ++n) acc[m][n] = (f32x4)(0.f);

    const char* Abase = (const char*)(A + (size_t)row0 * K);
    const char* Bbase = (const char*)(Bt + (size_t)col0 * K);

    int srow[4], skb[4];
#pragma unroll
    for (int i = 0; i < 4; ++i) {
        unsigned o = (unsigned)(i * 256 + tid) * 16u;
        unsigned l = o ^ (((o >> 7) & 7u) << 4);   // inverse-swizzled linear index
        srow[i] = (int)(l >> 7);
        skb[i]  = (int)(l & 127u);
    }

    for (int kt = 0; kt < K; kt += 64) {
#pragma unroll
        for (int i = 0; i < 4; ++i) {
            unsigned o = (unsigned)(i * 256 + tid) * 16u;
            gload_lds16(Abase + (size_t)srow[i] * (K * 2) + (size_t)kt * 2 + skb[i],
                        (char*)As + o);
            gload_lds16(Bbase + (size_t)srow[i] * (K * 2) + (size_t)kt * 2 + skb[i],
                        (char*)Bs + o);
        }
        asm volatile("s_waitcnt vmcnt(0)" ::: "memory");
        __syncthreads();
#pragma unroll
        for (int ks = 0; ks < 2; ++ks) {
            bf16x8 af[4], bfr[4];
#pragma unroll
            for (int m = 0; m < 4; ++m) {
                int row = wr * 64 + m * 16 + (lane & 15);
                unsigned o = (unsigned)(row * 128 + ks * 64 + ((lane >> 4) * 16));
                o ^= ((unsigned)(row & 7) << 4);
                af[m] = *(const bf16x8*)((const char*)As + o);
            }
#pragma unroll
            for (int n = 0; n < 4; ++n) {
                int col = wc * 64 + n * 16 + (lane & 15);
                unsigned o = (unsigned)(col * 128 + ks * 64 + ((lane >> 4) * 16));
                o ^= ((unsigned)(col & 7) << 4);
                bfr[n] = *(const bf16x8*)((const char*)Bs + o);
            }
#pragma unroll
            for (int m = 0; m < 4; ++m)
#pragma unroll
                for (int n = 0; n < 4; ++n)
                    acc[m][n] = __builtin_amdgcn_mfma_f32_16x16x32_bf16(
                        af[m], bfr[n], acc[m][n], 0, 0, 0);
        }
        __syncthreads();
    }

#pragma unroll
    for (int n = 0; n < 4; ++n) {
        int gcol = col0 + wc * 64 + n * 16 + (lane & 15);
        float bv = hasBias ? bias[gcol] : 0.f;
#pragma unroll
        for (int m = 0; m < 4; ++m) {
            int growb = row0 + wr * 64 + m * 16 + ((lane >> 4) * 4);
            float* cp = C + (size_t)growb * N + gcol;
#pragma unroll
            for (int r = 0; r < 4; ++r) cp[(size_t)r * N] = acc[m][n][r] + bv;
        }
    }
}

// ---------------- RNN scan v7: 2 waves per chain, lane-pair per col-pair ----------------
// Block = 128 thr = 2 waves = 1 chain (64 blocks). Lane = (pair p_, half q):
// owns cols {2G, 2G+1} (G = wv*32 + p_) x rows q*64..q*64+63.
// Weights: 64 f16x2 VGPRs (fits the ~132 budget -> no remat/spill).
// Per step: 8 broadcast ds_read_b128 (2 addr streams on same banks = free
// 2-way) -> 64 fdot2 -> ONE quad_perm DPP butterfly (both lanes get full
// sums) -> tanh both cols -> even lane writes LDS dword + hs dword.
// One lgkmcnt-only 2-wave barrier per step; h double-buffered.
__global__ __attribute__((amdgpu_flat_work_group_size(128, 128),
                          amdgpu_waves_per_eu(1, 1))) void k_scan(
    const float* __restrict__ xp,        // [M_][2048] fp32
    const float* __restrict__ h0,        // [B_][2048]
    const float* __restrict__ sw,        // [NH][HH][HH]
    unsigned short* __restrict__ hsb,    // [M_][2048] bf16 out
    float* __restrict__ out_state) {     // [B_][2048] fp32
    __shared__ __align__(16) unsigned hb[2][64];
    const int tid  = threadIdx.x;
    const int lane = tid & 63;
    const int wv   = tid >> 6;                // 0..1
    const int p_   = lane >> 1;               // pair in wave 0..31
    const int q    = lane & 1;                // row half
    const int G    = wv * 32 + p_;            // col-pair 0..63
    const int c0   = G * 2;
    const int bb = blockIdx.x >> 4;
    const int nn = blockIdx.x & 15;

    // wA[k]=(W[q*64+2k][c0], W[q*64+2k+1][c0]); wB same for col c0+1. k=0..31
    const float* wb = sw + (size_t)nn * HH * HH + (size_t)(q * 64) * HH + c0;
    f16x2 wA[32], wB[32];
#pragma unroll
    for (int k = 0; k < 32; ++k) {
        const float* r0p = wb + (size_t)(2 * k) * HH;
        const float* r1p = r0p + HH;
        wA[k] = f16x2{(_Float16)r0p[0], (_Float16)r1p[0]};
        wB[k] = f16x2{(_Float16)r0p[1], (_Float16)r1p[1]};
    }

    if (tid < 64) {   // init h: dword i = (h[2i], h[2i+1]) f16
        float2 h2 = *(const float2*)(h0 + bb * DST + nn * HH + 2 * tid);
        unsigned lo = __builtin_bit_cast(unsigned short, (_Float16)h2.x);
        unsigned hi = __builtin_bit_cast(unsigned short, (_Float16)h2.y);
        hb[0][tid] = lo | (hi << 16);
    }

    const float2* xrow2 = (const float2*)(xp + (size_t)bb * S_ * DST + nn * HH) + G;
    unsigned* hrow32 = (unsigned*)(hsb + (size_t)bb * S_ * DST + nn * HH) + G;
    float* osp = out_state + bb * DST + nn * HH + c0;

    // 4-deep xp prefetch (pair-uniform address)
    float2 xq0 = xrow2[0];
    float2 xq1 = xrow2[(size_t)(DST / 2)];
    float2 xq2 = xrow2[(size_t)2 * (DST / 2)];
    float2 xq3 = xrow2[(size_t)3 * (DST / 2)];

    asm volatile("s_waitcnt lgkmcnt(0)\ns_barrier" ::: "memory");

    int p = 0;
    for (int t = 0; t < S_; ++t) {
        int tpf = (t + 4 < S_) ? t + 4 : S_ - 1;
        float2 xq4 = xrow2[(size_t)tpf * (DST / 2)];

        const uint4* hp = (const uint4*)&hb[p][q * 32];
        float a0 = 0.f, a1 = 0.f, b0 = 0.f, b1 = 0.f;
#define DOT1(u, k, A, Bv) { f16x2 hk = __builtin_bit_cast(f16x2, (unsigned)(u)); \
        A = fdot2(hk, wA[k], A); Bv = fdot2(hk, wB[k], Bv); }
#pragma unroll
        for (int j = 0; j < 8; ++j) {
            uint4 R = hp[j];
            DOT1(R.x, 4 * j + 0, a0, b0)
            DOT1(R.y, 4 * j + 1, a1, b1)
            DOT1(R.z, 4 * j + 2, a0, b0)
            DOT1(R.w, 4 * j + 3, a1, b1)
        }
#undef DOT1
        float r0 = a0 + a1;
        float r1 = b0 + b1;
        // pair butterfly: both lanes end with the full 128-row sums
        r0 += DPP_PULL(r0, 0xB1);
        r1 += DPP_PULL(r1, 0xB1);

        float s0 = r0 + xq0.x;
        float s1 = r1 + xq0.y;
        // tanh(s) = 1 - 2/(exp(2s)+1), exact at +-inf
        float e0 = __builtin_amdgcn_exp2f(s0 * 2.885390081777927f);
        float e1 = __builtin_amdgcn_exp2f(s1 * 2.885390081777927f);
        float th0 = fmaf(-2.f, __builtin_amdgcn_rcpf(e0 + 1.f), 1.f);
        float th1 = fmaf(-2.f, __builtin_amdgcn_rcpf(e1 + 1.f), 1.f);

        if (q == 0) {
            unsigned lo = __builtin_bit_cast(unsigned short, (_Float16)th0);
            unsigned hi = __builtin_bit_cast(unsigned short, (_Float16)th1);
            hb[p ^ 1][G] = lo | (hi << 16);
            hrow32[(size_t)t * (DST / 2)] = (unsigned)f2bf(th0) | ((unsigned)f2bf(th1) << 16);
            if (t == S_ - 1) { osp[0] = th0; osp[1] = th1; }
        }
        asm volatile("s_waitcnt lgkmcnt(0)\ns_barrier" ::: "memory");
        p ^= 1;
        xq0 = xq1; xq1 = xq2; xq2 = xq3; xq3 = xq4;
    }
}

extern "C" void kernel_launch(void* const* d_in, const int* in_sizes, int n_in,
                              void* d_out, int out_size, void* d_ws, size_t ws_size,
                              hipStream_t stream) {
    const float* x    = (const float*)d_in[0];
    const float* h0   = (const float*)d_in[1];
    const float* Wi   = (const float*)d_in[2];
    const float* bias = (const float*)d_in[3];
    const float* sw   = (const float*)d_in[4];
    const float* Wo   = (const float*)d_in[5];
    float* out = (float*)d_out;

    char* ws = (char*)d_ws;
    unsigned short* xb  = (unsigned short*)ws;                     // 32MB (reused as hs bf16)
    unsigned short* wit = (unsigned short*)(ws + 33554432);        // 8MB
    unsigned short* wot = (unsigned short*)(ws + 41943040);        // 8MB
    float*          xp  = (float*)(ws + 50331648);                 // 64MB

    // 1. cast x -> bf16
    k_cast_bf16<<<8192, 256, 0, stream>>>(x, xb, (M_ * DIN) / 8);
    // 2. transpose+cast weights
    dim3 tg(32, 32);
    k_transpose_bf16<<<tg, 256, 0, stream>>>(Wi, wit, DIN, DST);
    k_transpose_bf16<<<tg, 256, 0, stream>>>(Wo, wot, DST, DOUT);
    // 3. xp = x @ Wi + b   (fp32 out)
    dim3 g1(DST / 128, M_ / 128);
    k_gemm_bt<<<g1, 256, 0, stream>>>(xb, wit, xp, bias, M_, DST, DIN, 1);
    // 4. sequential scan (2 waves per chain, 64 blocks x 128 threads)
    k_scan<<<64, 128, 0, stream>>>(xp, h0, sw, xb, out + OUT_OFF);
    // 5. out = hs @ Wo
    dim3 g2(DOUT / 128, M_ / 128);
    k_gemm_bt<<<g2, 256, 0, stream>>>(xb, wot, out, nullptr, M_, DOUT, DST, 0);
}